// Round 25
// baseline (88.519 us; speedup 1.0000x reference)
//
#include <hip/hip_runtime.h>

#define N_NODES 50000
#define N_EDGES 800000
#define D 64
#define NBUCK 782            // ceil(50000/64) buckets of 64 dst nodes
#define BINBLK 256           // bin blocks (1 per CU): runs of ~4 edges
#define EPB 3125             // edges per bin block (256*3125 = 800000)
#define ECHUNK 13            // ceil(3125/256)
#define GEMMBLK ((N_NODES + 15) / 16)   // 3125 gemm tiles, 16 rows each
#define CAP 1536             // bucket capacity (mean 1024 + 16 sigma)
#define FIXSCALE 4194304.0f  // 2^22 fixed-point for weighted degree

// ---------------- helpers ----------------

__device__ inline unsigned short f2bf(float f) {
    unsigned u = __float_as_uint(f);
    unsigned r = (u + 0x7FFFu + ((u >> 16) & 1u)) >> 16;   // RNE
    return (unsigned short)r;
}
__device__ inline float bf2f(unsigned short h) {
    return __uint_as_float(((unsigned)h) << 16);
}
__device__ inline int wave_incl_scan(int v, int lane) {
#pragma unroll
    for (int off = 1; off < 64; off <<= 1) {
        int n = __shfl_up(v, off, 64);
        if (lane >= off) v += n;
    }
    return v;
}

// ---------------- kernels ----------------

__global__ void k_zero(int* __restrict__ gcur) {
    int i = blockIdx.x * blockDim.x + threadIdx.x;
    if (i < NBUCK) gcur[i] = 0;
}

// Fused: blocks [0,BINBLK) bin edges into bucket regions (nt-loads on edge
// arrays, nt-stores on binned payloads — skip L2 write-allocate round-trip);
// blocks [BINBLK,..) compute hb = bf16(x @ W) with nt x-loads / hb-stores.
union ShU {
    int lh[NBUCK];                                   // bin: 3.1 KB
    struct { float Ws[D][D]; float Xs[4][D]; } gm;   // 17.4 KB
};
__global__ __launch_bounds__(256) void k_bin_gemm(
        const int* __restrict__ src, const int* __restrict__ dst,
        const float* __restrict__ ew,
        int* __restrict__ gcur, unsigned long long* __restrict__ binned,
        const float* __restrict__ x, const float* __restrict__ W,
        unsigned short* __restrict__ hb) {
    __shared__ ShU sh;
    int t = threadIdx.x;
    if (blockIdx.x < BINBLK) {
        int rd[ECHUNK]; int rs[ECHUNK]; float rw[ECHUNK];
        int* lh = sh.lh;
        for (int i = t; i < NBUCK; i += 256) lh[i] = 0;
        __syncthreads();
        int base = blockIdx.x * EPB;
#pragma unroll
        for (int i = 0; i < ECHUNK; ++i) {          // pass 1: nt-load + count
            int k = i * 256 + t;
            rd[i] = -1;
            if (k < EPB) {
                int e = base + k;
                rd[i] = __builtin_nontemporal_load(dst + e);
                rs[i] = __builtin_nontemporal_load(src + e);
                rw[i] = __builtin_nontemporal_load(ew + e);
                atomicAdd(&lh[rd[i] >> 6], 1);
            }
        }
        __syncthreads();
        for (int i = t; i < NBUCK; i += 256) {
            int c = lh[i];
            lh[i] = (c > 0) ? atomicAdd(&gcur[i], c) : 0;   // block's run base
        }
        __syncthreads();
#pragma unroll
        for (int i = 0; i < ECHUNK; ++i) {          // pass 2: nt scatter
            if (rd[i] >= 0) {
                int bkt = rd[i] >> 6;
                int pos = atomicAdd(&lh[bkt], 1);
                if (pos < CAP)
                    __builtin_nontemporal_store(
                        ((unsigned long long)__float_as_uint(rw[i]) << 32)
                      | ((unsigned)rs[i] << 16) | (unsigned)rd[i],
                        binned + (size_t)bkt * CAP + pos);
            }
        }
    } else {
        float (*Ws)[D] = sh.gm.Ws;
        float (*Xs)[D] = sh.gm.Xs;
        for (int k = t; k < D * D; k += 256) Ws[k / D][k % D] = W[k];
        int base = (blockIdx.x - BINBLK) * 16;
        int r = t >> 6, c = t & 63;
        for (int g = 0; g < 4; ++g) {
            int row = base + g * 4 + r;
            __syncthreads();   // covers Ws staging (g=0) and Xs reuse (g>0)
            Xs[r][c] = (row < N_NODES)
                         ? __builtin_nontemporal_load(x + (size_t)row * D + c)
                         : 0.0f;
            __syncthreads();
            float acc = 0.0f;
#pragma unroll
            for (int k = 0; k < D; ++k) acc = fmaf(Xs[r][k], Ws[k][c], acc);
            if (row < N_NODES)
                __builtin_nontemporal_store(f2bf(acc), hb + (size_t)row * D + c);
        }
    }
}

// one block per bucket (R17-proven): counting-sort to per-node CSR
// (u32 bf16ew|src); fused weighted degree -> dinv; rc = (cnt<<12)|excl
__global__ void k_sortbucket(const unsigned long long* __restrict__ binned,
                             const int* __restrict__ gcur,
                             unsigned* __restrict__ csr,
                             unsigned* __restrict__ rc,
                             float* __restrict__ dinv) {
    __shared__ unsigned long long stage[CAP];   // 12 KB
    __shared__ unsigned long long cw[64];       // (cnt<<40) | fix22 wsum
    __shared__ int off2[64];
    int t = threadIdx.x;
    if (t < 64) cw[t] = 0ULL;
    __syncthreads();
    int b = blockIdx.x;
    size_t beg = (size_t)b * CAP;
    int len = min(gcur[b], CAP);
    for (int k = t; k < len; k += 256) {
        unsigned long long p = binned[beg + k];
        stage[k] = p;
        int dl = (int)(p & 63);
        float w = __uint_as_float((unsigned)(p >> 32));
        atomicAdd(&cw[dl], (1ULL << 40) | (unsigned long long)__float2uint_rn(w * FIXSCALE));
    }
    __syncthreads();
    if (t < 64) {
        int c = (int)(cw[t] >> 40);
        float wfix = (float)(cw[t] & ((1ULL << 40) - 1ULL));
        int inc = wave_incl_scan(c, t);
        int excl = inc - c;
        off2[t] = excl;
        int node = b * 64 + t;
        if (node < N_NODES) {
            rc[node] = ((unsigned)c << 12) | (unsigned)excl;
            dinv[node] = rsqrtf(1.0f + wfix * (1.0f / FIXSCALE));
        }
    }
    __syncthreads();
    for (int k = t; k < len; k += 256) {
        unsigned long long p = stage[k];
        int dl = (int)(p & 63);
        int r = atomicAdd(&off2[dl], 1);
        unsigned short ewb = f2bf(__uint_as_float((unsigned)(p >> 32)));
        csr[beg + r] = ((unsigned)ewb << 16) | (unsigned)((p >> 16) & 0xffffu);
    }
}

// one wave per node, EIGHT 8-lane octants; octant o handles edge jp+o.
// Each lane loads uint4 = 8 bf16 cols (16 B; 128 B/row coalesced).
// Control flow wave-uniform; masked tail with multiplier zeroing.
// out written non-temporally (never re-read).
__global__ void k_aggregate(const unsigned short* __restrict__ hb,
                            const float* __restrict__ dinv,
                            const unsigned* __restrict__ rc,
                            const unsigned* __restrict__ csr,
                            const float* __restrict__ bias,
                            float* __restrict__ out) {
    int node = blockIdx.x * 4 + (threadIdx.x >> 6);
    int lane = threadIdx.x & 63;
    if (node >= N_NODES) return;
    int oct = lane >> 3;         // 0..7
    int c8 = lane & 7;           // col group: cols 8*c8 .. 8*c8+7
    float di = dinv[node];
    unsigned r = rc[node];
    int cnt = (int)(r >> 12);
    size_t beg = (size_t)(node >> 6) * CAP + (r & 0xFFFu);
    float a[8], p[8];
    {   // self-loop term, counted once (octant 0)
        uint4 hd = *(const uint4*)(hb + (size_t)node * D + 8 * c8);
        float m = (oct == 0) ? di : 0.0f;
        a[0] = m * bf2f((unsigned short)hd.x);
        a[1] = m * bf2f((unsigned short)(hd.x >> 16));
        a[2] = m * bf2f((unsigned short)hd.y);
        a[3] = m * bf2f((unsigned short)(hd.y >> 16));
        a[4] = m * bf2f((unsigned short)hd.z);
        a[5] = m * bf2f((unsigned short)(hd.z >> 16));
        a[6] = m * bf2f((unsigned short)hd.w);
        a[7] = m * bf2f((unsigned short)(hd.w >> 16));
    }
#pragma unroll
    for (int i = 0; i < 8; ++i) p[i] = 0.0f;
    for (int b0 = 0; b0 < cnt; b0 += 64) {
        int n = min(64, cnt - b0);
        int my_src = 0;
        float my_ew = 0.0f;
        if (lane < n) {
            unsigned q = csr[beg + b0 + lane];
            my_src = (int)(q & 0xffffu);
            my_ew = bf2f((unsigned short)(q >> 16)) * dinv[my_src];  // L2-resident
        }
        int jp = 0;
        for (; jp + 16 <= n; jp += 16) {   // full groups: iA,iB < n guaranteed
            int iA = jp + oct, iB = iA + 8;
            int sA = __shfl(my_src, iA, 64);
            float eA = __shfl(my_ew, iA, 64);
            int sB = __shfl(my_src, iB, 64);
            float eB = __shfl(my_ew, iB, 64);
            uint4 hA = *(const uint4*)(hb + (size_t)sA * D + 8 * c8);
            uint4 hB = *(const uint4*)(hb + (size_t)sB * D + 8 * c8);
            a[0] = fmaf(bf2f((unsigned short)hA.x), eA, a[0]);
            a[1] = fmaf(bf2f((unsigned short)(hA.x >> 16)), eA, a[1]);
            a[2] = fmaf(bf2f((unsigned short)hA.y), eA, a[2]);
            a[3] = fmaf(bf2f((unsigned short)(hA.y >> 16)), eA, a[3]);
            a[4] = fmaf(bf2f((unsigned short)hA.z), eA, a[4]);
            a[5] = fmaf(bf2f((unsigned short)(hA.z >> 16)), eA, a[5]);
            a[6] = fmaf(bf2f((unsigned short)hA.w), eA, a[6]);
            a[7] = fmaf(bf2f((unsigned short)(hA.w >> 16)), eA, a[7]);
            p[0] = fmaf(bf2f((unsigned short)hB.x), eB, p[0]);
            p[1] = fmaf(bf2f((unsigned short)(hB.x >> 16)), eB, p[1]);
            p[2] = fmaf(bf2f((unsigned short)hB.y), eB, p[2]);
            p[3] = fmaf(bf2f((unsigned short)(hB.y >> 16)), eB, p[3]);
            p[4] = fmaf(bf2f((unsigned short)hB.z), eB, p[4]);
            p[5] = fmaf(bf2f((unsigned short)(hB.z >> 16)), eB, p[5]);
            p[6] = fmaf(bf2f((unsigned short)hB.w), eB, p[6]);
            p[7] = fmaf(bf2f((unsigned short)(hB.w >> 16)), eB, p[7]);
        }
        if (jp < n) {                      // masked tail (≤15 edges), uniform
            int iA = jp + oct, iB = iA + 8;   // jp ≤ 48 -> iB ≤ 63
            int sA = __shfl(my_src, iA, 64);
            float eA = __shfl(my_ew, iA, 64);
            int sB = __shfl(my_src, iB, 64);
            float eB = __shfl(my_ew, iB, 64);
            eA = (iA < n) ? eA : 0.0f;
            eB = (iB < n) ? eB : 0.0f;
            uint4 hA = *(const uint4*)(hb + (size_t)sA * D + 8 * c8);
            uint4 hB = *(const uint4*)(hb + (size_t)sB * D + 8 * c8);
            a[0] = fmaf(bf2f((unsigned short)hA.x), eA, a[0]);
            a[1] = fmaf(bf2f((unsigned short)(hA.x >> 16)), eA, a[1]);
            a[2] = fmaf(bf2f((unsigned short)hA.y), eA, a[2]);
            a[3] = fmaf(bf2f((unsigned short)(hA.y >> 16)), eA, a[3]);
            a[4] = fmaf(bf2f((unsigned short)hA.z), eA, a[4]);
            a[5] = fmaf(bf2f((unsigned short)(hA.z >> 16)), eA, a[5]);
            a[6] = fmaf(bf2f((unsigned short)hA.w), eA, a[6]);
            a[7] = fmaf(bf2f((unsigned short)(hA.w >> 16)), eA, a[7]);
            p[0] = fmaf(bf2f((unsigned short)hB.x), eB, p[0]);
            p[1] = fmaf(bf2f((unsigned short)(hB.x >> 16)), eB, p[1]);
            p[2] = fmaf(bf2f((unsigned short)hB.y), eB, p[2]);
            p[3] = fmaf(bf2f((unsigned short)(hB.y >> 16)), eB, p[3]);
            p[4] = fmaf(bf2f((unsigned short)hB.z), eB, p[4]);
            p[5] = fmaf(bf2f((unsigned short)(hB.z >> 16)), eB, p[5]);
            p[6] = fmaf(bf2f((unsigned short)hB.w), eB, p[6]);
            p[7] = fmaf(bf2f((unsigned short)(hB.w >> 16)), eB, p[7]);
        }
    }
#pragma unroll
    for (int i = 0; i < 8; ++i) {
        a[i] += p[i];
        a[i] += __shfl_xor(a[i], 8, 64);
        a[i] += __shfl_xor(a[i], 16, 64);
        a[i] += __shfl_xor(a[i], 32, 64);
    }
    if (oct == 0) {
        float o[8];
#pragma unroll
        for (int i = 0; i < 8; ++i)
            o[i] = fmaxf(fmaf(di, a[i], bias[8 * c8 + i]), 0.0f);
        float* op = out + (size_t)node * D + 8 * c8;
#pragma unroll
        for (int i = 0; i < 8; ++i)
            __builtin_nontemporal_store(o[i], op + i);
    }
}

// ---------------- launch ----------------

extern "C" void kernel_launch(void* const* d_in, const int* in_sizes, int n_in,
                              void* d_out, int out_size, void* d_ws, size_t ws_size,
                              hipStream_t stream) {
    const float* x  = (const float*)d_in[0];
    const int*   ei = (const int*)d_in[1];    // [2, E] row-major, int32
    const float* ew = (const float*)d_in[2];
    const float* W  = (const float*)d_in[3];
    const float* b  = (const float*)d_in[4];
    float* out = (float*)d_out;

    const int* src = ei;
    const int* dst = ei + N_EDGES;

    // workspace layout (8B-aligned first)
    unsigned long long* binned = (unsigned long long*)d_ws;          // NBUCK*CAP u64 (9.6MB)
    unsigned* csr      = (unsigned*)(binned + (size_t)NBUCK * CAP);  // NBUCK*CAP u32 (4.8MB)
    int*   gcur        = (int*)(csr + (size_t)NBUCK * CAP);          // 1024
    unsigned* rc       = (unsigned*)(gcur + 1024);                   // 50048
    float* dinv        = (float*)(rc + 50048);                       // 50048
    unsigned short* hb = (unsigned short*)(dinv + 50048);            // N*D bf16 (6.4MB)

    dim3 blk(256);
    k_zero<<<4, blk, 0, stream>>>(gcur);
    k_bin_gemm<<<BINBLK + GEMMBLK, blk, 0, stream>>>(src, dst, ew, gcur, binned,
                                                     x, W, hb);
    k_sortbucket<<<NBUCK, blk, 0, stream>>>(binned, gcur, csr, rc, dinv);
    k_aggregate<<<(N_NODES + 3) / 4, blk, 0, stream>>>(hb, dinv, rc, csr, b, out);
}

// Round 26
// 72.606 us; speedup vs baseline: 1.2192x; 1.2192x over previous
//
#include <hip/hip_runtime.h>

#define N_NODES 50000
#define N_EDGES 800000
#define D 64
#define NBUCK 782            // ceil(50000/64) buckets of 64 dst nodes
#define BINBLK 256           // bin blocks (1 per CU): runs of ~4 edges
#define EPB 3125             // edges per bin block (256*3125 = 800000)
#define ECHUNK 13            // ceil(3125/256)
#define GEMMBLK ((N_NODES + 15) / 16)   // 3125 gemm tiles, 16 rows each
#define CAP 1536             // bucket capacity (mean 1024 + 16 sigma)
#define FIXSCALE 4194304.0f  // 2^22 fixed-point for weighted degree

// ---------------- helpers ----------------

__device__ inline unsigned short f2bf(float f) {
    unsigned u = __float_as_uint(f);
    unsigned r = (u + 0x7FFFu + ((u >> 16) & 1u)) >> 16;   // RNE
    return (unsigned short)r;
}
__device__ inline float bf2f(unsigned short h) {
    return __uint_as_float(((unsigned)h) << 16);
}
__device__ inline int wave_incl_scan(int v, int lane) {
#pragma unroll
    for (int off = 1; off < 64; off <<= 1) {
        int n = __shfl_up(v, off, 64);
        if (lane >= off) v += n;
    }
    return v;
}

// ---------------- kernels ----------------

__global__ void k_zero(int* __restrict__ gcur) {
    int i = blockIdx.x * blockDim.x + threadIdx.x;
    if (i < NBUCK) gcur[i] = 0;
}

// Fused (R17-proven): blocks [0,BINBLK) bin edges into bucket regions;
// blocks [BINBLK,..) compute hb = bf16(x @ W). gcur DENSE; regular
// (write-allocating) stores — L2 allocation is what merges the runs (R25).
union ShU {
    int lh[NBUCK];                                   // bin: 3.1 KB
    struct { float Ws[D][D]; float Xs[4][D]; } gm;   // 17.4 KB
};
__global__ __launch_bounds__(256) void k_bin_gemm(
        const int* __restrict__ src, const int* __restrict__ dst,
        const float* __restrict__ ew,
        int* __restrict__ gcur, unsigned long long* __restrict__ binned,
        const float* __restrict__ x, const float* __restrict__ W,
        unsigned short* __restrict__ hb) {
    __shared__ ShU sh;
    int t = threadIdx.x;
    if (blockIdx.x < BINBLK) {
        int rd[ECHUNK]; int rs[ECHUNK]; float rw[ECHUNK];
        int* lh = sh.lh;
        for (int i = t; i < NBUCK; i += 256) lh[i] = 0;
        __syncthreads();
        int base = blockIdx.x * EPB;
#pragma unroll
        for (int i = 0; i < ECHUNK; ++i) {          // pass 1: load + count
            int k = i * 256 + t;
            rd[i] = -1;
            if (k < EPB) {
                int e = base + k;
                rd[i] = dst[e];
                rs[i] = src[e];
                rw[i] = ew[e];
                atomicAdd(&lh[rd[i] >> 6], 1);
            }
        }
        __syncthreads();
        for (int i = t; i < NBUCK; i += 256) {
            int c = lh[i];
            lh[i] = (c > 0) ? atomicAdd(&gcur[i], c) : 0;   // block's run base
        }
        __syncthreads();
#pragma unroll
        for (int i = 0; i < ECHUNK; ++i) {          // pass 2: scatter from regs
            if (rd[i] >= 0) {
                int bkt = rd[i] >> 6;
                int pos = atomicAdd(&lh[bkt], 1);
                if (pos < CAP)
                    binned[(size_t)bkt * CAP + pos] =
                        ((unsigned long long)__float_as_uint(rw[i]) << 32)
                      | ((unsigned)rs[i] << 16) | (unsigned)rd[i];
            }
        }
    } else {
        float (*Ws)[D] = sh.gm.Ws;
        float (*Xs)[D] = sh.gm.Xs;
        for (int k = t; k < D * D; k += 256) Ws[k / D][k % D] = W[k];
        int base = (blockIdx.x - BINBLK) * 16;
        int r = t >> 6, c = t & 63;
        for (int g = 0; g < 4; ++g) {
            int row = base + g * 4 + r;
            __syncthreads();   // covers Ws staging (g=0) and Xs reuse (g>0)
            Xs[r][c] = (row < N_NODES) ? x[(size_t)row * D + c] : 0.0f;
            __syncthreads();
            float acc = 0.0f;
#pragma unroll
            for (int k = 0; k < D; ++k) acc = fmaf(Xs[r][k], Ws[k][c], acc);
            if (row < N_NODES) hb[(size_t)row * D + c] = f2bf(acc);
        }
    }
}

// one block per bucket (R17-proven): counting-sort to per-node CSR
// (u32 bf16ew|src); fused weighted degree -> dinv; rc = (cnt<<12)|excl
__global__ void k_sortbucket(const unsigned long long* __restrict__ binned,
                             const int* __restrict__ gcur,
                             unsigned* __restrict__ csr,
                             unsigned* __restrict__ rc,
                             float* __restrict__ dinv) {
    __shared__ unsigned long long stage[CAP];   // 12 KB
    __shared__ unsigned long long cw[64];       // (cnt<<40) | fix22 wsum
    __shared__ int off2[64];
    int t = threadIdx.x;
    if (t < 64) cw[t] = 0ULL;
    __syncthreads();
    int b = blockIdx.x;
    size_t beg = (size_t)b * CAP;
    int len = min(gcur[b], CAP);
    for (int k = t; k < len; k += 256) {
        unsigned long long p = binned[beg + k];
        stage[k] = p;
        int dl = (int)(p & 63);
        float w = __uint_as_float((unsigned)(p >> 32));
        atomicAdd(&cw[dl], (1ULL << 40) | (unsigned long long)__float2uint_rn(w * FIXSCALE));
    }
    __syncthreads();
    if (t < 64) {
        int c = (int)(cw[t] >> 40);
        float wfix = (float)(cw[t] & ((1ULL << 40) - 1ULL));
        int inc = wave_incl_scan(c, t);
        int excl = inc - c;
        off2[t] = excl;
        int node = b * 64 + t;
        if (node < N_NODES) {
            rc[node] = ((unsigned)c << 12) | (unsigned)excl;
            dinv[node] = rsqrtf(1.0f + wfix * (1.0f / FIXSCALE));
        }
    }
    __syncthreads();
    for (int k = t; k < len; k += 256) {
        unsigned long long p = stage[k];
        int dl = (int)(p & 63);
        int r = atomicAdd(&off2[dl], 1);
        unsigned short ewb = f2bf(__uint_as_float((unsigned)(p >> 32)));
        csr[beg + r] = ((unsigned)ewb << 16) | (unsigned)((p >> 16) & 0xffffu);
    }
}

// one wave per node, EIGHT 8-lane octants; octant o handles edge jp+o.
// Each lane loads uint4 = 8 bf16 cols (16 B; 128 B/row coalesced).
// Control flow wave-uniform; masked tail with multiplier zeroing.
__global__ void k_aggregate(const unsigned short* __restrict__ hb,
                            const float* __restrict__ dinv,
                            const unsigned* __restrict__ rc,
                            const unsigned* __restrict__ csr,
                            const float* __restrict__ bias,
                            float* __restrict__ out) {
    int node = blockIdx.x * 4 + (threadIdx.x >> 6);
    int lane = threadIdx.x & 63;
    if (node >= N_NODES) return;
    int oct = lane >> 3;         // 0..7
    int c8 = lane & 7;           // col group: cols 8*c8 .. 8*c8+7
    float di = dinv[node];
    unsigned r = rc[node];
    int cnt = (int)(r >> 12);
    size_t beg = (size_t)(node >> 6) * CAP + (r & 0xFFFu);
    float a[8], p[8];
    {   // self-loop term, counted once (octant 0)
        uint4 hd = *(const uint4*)(hb + (size_t)node * D + 8 * c8);
        float m = (oct == 0) ? di : 0.0f;
        a[0] = m * bf2f((unsigned short)hd.x);
        a[1] = m * bf2f((unsigned short)(hd.x >> 16));
        a[2] = m * bf2f((unsigned short)hd.y);
        a[3] = m * bf2f((unsigned short)(hd.y >> 16));
        a[4] = m * bf2f((unsigned short)hd.z);
        a[5] = m * bf2f((unsigned short)(hd.z >> 16));
        a[6] = m * bf2f((unsigned short)hd.w);
        a[7] = m * bf2f((unsigned short)(hd.w >> 16));
    }
#pragma unroll
    for (int i = 0; i < 8; ++i) p[i] = 0.0f;
    for (int b0 = 0; b0 < cnt; b0 += 64) {
        int n = min(64, cnt - b0);
        int my_src = 0;
        float my_ew = 0.0f;
        if (lane < n) {
            unsigned q = csr[beg + b0 + lane];
            my_src = (int)(q & 0xffffu);
            my_ew = bf2f((unsigned short)(q >> 16)) * dinv[my_src];  // L2-resident
        }
        int jp = 0;
        for (; jp + 16 <= n; jp += 16) {   // full groups: iA,iB < n guaranteed
            int iA = jp + oct, iB = iA + 8;
            int sA = __shfl(my_src, iA, 64);
            float eA = __shfl(my_ew, iA, 64);
            int sB = __shfl(my_src, iB, 64);
            float eB = __shfl(my_ew, iB, 64);
            uint4 hA = *(const uint4*)(hb + (size_t)sA * D + 8 * c8);
            uint4 hB = *(const uint4*)(hb + (size_t)sB * D + 8 * c8);
            a[0] = fmaf(bf2f((unsigned short)hA.x), eA, a[0]);
            a[1] = fmaf(bf2f((unsigned short)(hA.x >> 16)), eA, a[1]);
            a[2] = fmaf(bf2f((unsigned short)hA.y), eA, a[2]);
            a[3] = fmaf(bf2f((unsigned short)(hA.y >> 16)), eA, a[3]);
            a[4] = fmaf(bf2f((unsigned short)hA.z), eA, a[4]);
            a[5] = fmaf(bf2f((unsigned short)(hA.z >> 16)), eA, a[5]);
            a[6] = fmaf(bf2f((unsigned short)hA.w), eA, a[6]);
            a[7] = fmaf(bf2f((unsigned short)(hA.w >> 16)), eA, a[7]);
            p[0] = fmaf(bf2f((unsigned short)hB.x), eB, p[0]);
            p[1] = fmaf(bf2f((unsigned short)(hB.x >> 16)), eB, p[1]);
            p[2] = fmaf(bf2f((unsigned short)hB.y), eB, p[2]);
            p[3] = fmaf(bf2f((unsigned short)(hB.y >> 16)), eB, p[3]);
            p[4] = fmaf(bf2f((unsigned short)hB.z), eB, p[4]);
            p[5] = fmaf(bf2f((unsigned short)(hB.z >> 16)), eB, p[5]);
            p[6] = fmaf(bf2f((unsigned short)hB.w), eB, p[6]);
            p[7] = fmaf(bf2f((unsigned short)(hB.w >> 16)), eB, p[7]);
        }
        if (jp < n) {                      // masked tail (≤15 edges), uniform
            int iA = jp + oct, iB = iA + 8;   // jp ≤ 48 -> iB ≤ 63
            int sA = __shfl(my_src, iA, 64);
            float eA = __shfl(my_ew, iA, 64);
            int sB = __shfl(my_src, iB, 64);
            float eB = __shfl(my_ew, iB, 64);
            eA = (iA < n) ? eA : 0.0f;
            eB = (iB < n) ? eB : 0.0f;
            uint4 hA = *(const uint4*)(hb + (size_t)sA * D + 8 * c8);
            uint4 hB = *(const uint4*)(hb + (size_t)sB * D + 8 * c8);
            a[0] = fmaf(bf2f((unsigned short)hA.x), eA, a[0]);
            a[1] = fmaf(bf2f((unsigned short)(hA.x >> 16)), eA, a[1]);
            a[2] = fmaf(bf2f((unsigned short)hA.y), eA, a[2]);
            a[3] = fmaf(bf2f((unsigned short)(hA.y >> 16)), eA, a[3]);
            a[4] = fmaf(bf2f((unsigned short)hA.z), eA, a[4]);
            a[5] = fmaf(bf2f((unsigned short)(hA.z >> 16)), eA, a[5]);
            a[6] = fmaf(bf2f((unsigned short)hA.w), eA, a[6]);
            a[7] = fmaf(bf2f((unsigned short)(hA.w >> 16)), eA, a[7]);
            p[0] = fmaf(bf2f((unsigned short)hB.x), eB, p[0]);
            p[1] = fmaf(bf2f((unsigned short)(hB.x >> 16)), eB, p[1]);
            p[2] = fmaf(bf2f((unsigned short)hB.y), eB, p[2]);
            p[3] = fmaf(bf2f((unsigned short)(hB.y >> 16)), eB, p[3]);
            p[4] = fmaf(bf2f((unsigned short)hB.z), eB, p[4]);
            p[5] = fmaf(bf2f((unsigned short)(hB.z >> 16)), eB, p[5]);
            p[6] = fmaf(bf2f((unsigned short)hB.w), eB, p[6]);
            p[7] = fmaf(bf2f((unsigned short)(hB.w >> 16)), eB, p[7]);
        }
    }
#pragma unroll
    for (int i = 0; i < 8; ++i) {
        a[i] += p[i];
        a[i] += __shfl_xor(a[i], 8, 64);
        a[i] += __shfl_xor(a[i], 16, 64);
        a[i] += __shfl_xor(a[i], 32, 64);
    }
    if (oct == 0) {
        float4 o0, o1;
        o0.x = fmaxf(fmaf(di, a[0], bias[8 * c8 + 0]), 0.0f);
        o0.y = fmaxf(fmaf(di, a[1], bias[8 * c8 + 1]), 0.0f);
        o0.z = fmaxf(fmaf(di, a[2], bias[8 * c8 + 2]), 0.0f);
        o0.w = fmaxf(fmaf(di, a[3], bias[8 * c8 + 3]), 0.0f);
        o1.x = fmaxf(fmaf(di, a[4], bias[8 * c8 + 4]), 0.0f);
        o1.y = fmaxf(fmaf(di, a[5], bias[8 * c8 + 5]), 0.0f);
        o1.z = fmaxf(fmaf(di, a[6], bias[8 * c8 + 6]), 0.0f);
        o1.w = fmaxf(fmaf(di, a[7], bias[8 * c8 + 7]), 0.0f);
        *(float4*)(out + (size_t)node * D + 8 * c8) = o0;
        *(float4*)(out + (size_t)node * D + 8 * c8 + 4) = o1;
    }
}

// ---------------- launch ----------------

extern "C" void kernel_launch(void* const* d_in, const int* in_sizes, int n_in,
                              void* d_out, int out_size, void* d_ws, size_t ws_size,
                              hipStream_t stream) {
    const float* x  = (const float*)d_in[0];
    const int*   ei = (const int*)d_in[1];    // [2, E] row-major, int32
    const float* ew = (const float*)d_in[2];
    const float* W  = (const float*)d_in[3];
    const float* b  = (const float*)d_in[4];
    float* out = (float*)d_out;

    const int* src = ei;
    const int* dst = ei + N_EDGES;

    // workspace layout (8B-aligned first)
    unsigned long long* binned = (unsigned long long*)d_ws;          // NBUCK*CAP u64 (9.6MB)
    unsigned* csr      = (unsigned*)(binned + (size_t)NBUCK * CAP);  // NBUCK*CAP u32 (4.8MB)
    int*   gcur        = (int*)(csr + (size_t)NBUCK * CAP);          // 1024
    unsigned* rc       = (unsigned*)(gcur + 1024);                   // 50048
    float* dinv        = (float*)(rc + 50048);                       // 50048
    unsigned short* hb = (unsigned short*)(dinv + 50048);            // N*D bf16 (6.4MB)

    dim3 blk(256);
    k_zero<<<4, blk, 0, stream>>>(gcur);
    k_bin_gemm<<<BINBLK + GEMMBLK, blk, 0, stream>>>(src, dst, ew, gcur, binned,
                                                     x, W, hb);
    k_sortbucket<<<NBUCK, blk, 0, stream>>>(binned, gcur, csr, rc, dinv);
    k_aggregate<<<(N_NODES + 3) / 4, blk, 0, stream>>>(hb, dinv, rc, csr, b, out);
}